// Round 7
// baseline (320.278 us; speedup 1.0000x reference)
//
#include <hip/hip_runtime.h>

typedef __attribute__((ext_vector_type(8))) __bf16 bf16x8;
typedef __attribute__((ext_vector_type(4))) __bf16 bf16x4;
typedef __attribute__((ext_vector_type(4))) float f32x4;
typedef __attribute__((ext_vector_type(16))) float f32x16;

#define LL 2048
#define DD 2048
#define HH 16
#define HDIM 128

// ---------------- fp32 -> bf16 conversion ----------------
__global__ void cvt_f32_bf16(const float* __restrict__ src, __bf16* __restrict__ dst, int n4)
{
    int i = blockIdx.x * blockDim.x + threadIdx.x;
    if (i < n4) {
        float4 v = *(const float4*)(src + (size_t)i * 4);
        bf16x4 o = { (__bf16)v.x, (__bf16)v.y, (__bf16)v.z, (__bf16)v.w };
        *(bf16x4*)(dst + (size_t)i * 4) = o;
    }
}

// 4 big weight arrays (2048x2048 = 1048576 float4 each) in one launch
__global__ void cvt_w_big(const float* __restrict__ a0, const float* __restrict__ a1,
                          const float* __restrict__ a2, const float* __restrict__ a3,
                          __bf16* __restrict__ o0, __bf16* __restrict__ o1,
                          __bf16* __restrict__ o2, __bf16* __restrict__ o3)
{
    const float* s[4] = { a0, a1, a2, a3 };
    __bf16* d[4] = { o0, o1, o2, o3 };
    const int w = blockIdx.y;
    const int i = blockIdx.x * 256 + threadIdx.x;   // needs 4096 blocks in x
    float4 v = *(const float4*)(s[w] + (size_t)i * 4);
    bf16x4 o = { (__bf16)v.x, (__bf16)v.y, (__bf16)v.z, (__bf16)v.w };
    *(bf16x4*)(d[w] + (size_t)i * 4) = o;
}

// small-weights conversion: 4 arrays of 4096 floats each
__global__ void cvt_w4(const float* __restrict__ a0, const float* __restrict__ a1,
                       const float* __restrict__ a2, const float* __restrict__ a3,
                       __bf16* __restrict__ o0, __bf16* __restrict__ o1,
                       __bf16* __restrict__ o2, __bf16* __restrict__ o3)
{
    const float* s[4] = { a0, a1, a2, a3 };
    __bf16* d[4] = { o0, o1, o2, o3 };
    const int w = blockIdx.y;
    const int i = blockIdx.x * 256 + threadIdx.x;
    float4 v = *(const float4*)(s[w] + (size_t)i * 4);
    bf16x4 o = { (__bf16)v.x, (__bf16)v.y, (__bf16)v.z, (__bf16)v.w };
    *(bf16x4*)(d[w] + (size_t)i * 4) = o;
}

// ---------------- global -> LDS async 16B ----------------
typedef unsigned int u32;
typedef const __attribute__((address_space(1))) u32* gp_t;
typedef __attribute__((address_space(3))) u32* lp_t;
__device__ __forceinline__ void gload16(const __bf16* g, __bf16* l)
{
    __builtin_amdgcn_global_load_lds((gp_t)(const void*)g, (lp_t)(void*)l, 16, 0, 0);
}

// ---------------- bf16 GEMM tile body (m97 structure) ----------------
// 128x128 tile, BK=64, 4 waves (2x2), linear LDS, global_load_lds width-16.
template<bool OUT_BF16>
__device__ __forceinline__ void gemm_tile_body(
    const __bf16* __restrict__ A, const __bf16* __restrict__ W,
    const float* __restrict__ bias, void* __restrict__ Cout,
    int m0, int n0, int N, int K,
    __bf16 (*As)[64], __bf16 (*Bs)[64])
{
    const int tid  = threadIdx.x;
    const int wave = tid >> 6;
    const int lane = tid & 63;
    const int wr   = (wave >> 1) * 64;
    const int wc   = (wave & 1) * 64;
    const int lr   = lane & 15;
    const int lk   = (lane >> 4) * 8;
    const int srow = wave * 32 + (lane >> 3);
    const int scol = (lane & 7) * 8;

    f32x4 acc[4][4] = {};
    const __bf16* Aw = A + (size_t)(m0 + srow) * K + scol;
    const __bf16* Ww = W + (size_t)(n0 + srow) * K + scol;
    __bf16* lA = &As[wave * 32][0];    // wave-uniform base; HW adds lane*16B
    __bf16* lB = &Bs[wave * 32][0];

    for (int k0 = 0; k0 < K; k0 += 64) {
        #pragma unroll
        for (int j = 0; j < 4; ++j) {
            gload16(Aw + (size_t)(j * 8) * K + k0, lA + j * 512);
            gload16(Ww + (size_t)(j * 8) * K + k0, lB + j * 512);
        }
        __syncthreads();
        #pragma unroll
        for (int ks = 0; ks < 2; ++ks) {
            bf16x8 af[4], bfr[4];
            #pragma unroll
            for (int m = 0; m < 4; ++m)
                af[m] = *(const bf16x8*)(&As[wr + m * 16 + lr][ks * 32 + lk]);
            #pragma unroll
            for (int n = 0; n < 4; ++n)
                bfr[n] = *(const bf16x8*)(&Bs[wc + n * 16 + lr][ks * 32 + lk]);
            #pragma unroll
            for (int m = 0; m < 4; ++m)
                #pragma unroll
                for (int n = 0; n < 4; ++n)
                    acc[m][n] = __builtin_amdgcn_mfma_f32_16x16x32_bf16(af[m], bfr[n], acc[m][n], 0, 0, 0);
        }
        __syncthreads();
    }

    const int orow = (lane >> 4) * 4;
    #pragma unroll
    for (int n = 0; n < 4; ++n) {
        const int col = n0 + wc + n * 16 + lr;
        const float bv = bias[col];
        #pragma unroll
        for (int m = 0; m < 4; ++m) {
            #pragma unroll
            for (int r = 0; r < 4; ++r) {
                const int row = m0 + wr + m * 16 + orow + r;
                const float v = acc[m][n][r] + bv;
                if (OUT_BF16) ((__bf16*)Cout)[(size_t)row * N + col] = (__bf16)v;
                else          ((float*)Cout)[(size_t)row * N + col]  = v;
            }
        }
    }
}

// Fused QKV GEMM: A(4096x2048) x {Wq,Wk,Wv}(2048x2048)^T, 1536 blocks, XCD swizzle.
__global__ __launch_bounds__(256)
void gemm_qkv(const __bf16* __restrict__ A,
              const __bf16* __restrict__ W0, const __bf16* __restrict__ W1,
              const __bf16* __restrict__ W2,
              const float* __restrict__ b0, const float* __restrict__ b1,
              const float* __restrict__ b2,
              __bf16* __restrict__ C0, __bf16* __restrict__ C1, __bf16* __restrict__ C2)
{
    __shared__ __bf16 As[128][64];
    __shared__ __bf16 Bs[128][64];
    const int bid = blockIdx.x;                       // 1536 blocks, 1536%8==0
    const int swz = (bid & 7) * 192 + (bid >> 3);     // XCD-contiguous chunks
    const int bx  = swz % 48;                         // n-tile 0..47 (fastest: A reuse)
    const int by  = swz / 48;                         // m-tile 0..31
    const int which = bx >> 4;
    const int n0    = (bx & 15) * 128;
    const __bf16* W  = which == 0 ? W0 : which == 1 ? W1 : W2;
    const float*  bb = which == 0 ? b0 : which == 1 ? b1 : b2;
    __bf16*       C  = which == 0 ? C0 : which == 1 ? C1 : C2;
    gemm_tile_body<true>(A, W, bb, C, by * 128, n0, 2048, 2048, As, Bs);
}

// Output GEMM: A(4096x2048) x Wo(2048x2048)^T -> f32, 512 blocks, XCD swizzle.
__global__ __launch_bounds__(256)
void gemm_wo(const __bf16* __restrict__ A, const __bf16* __restrict__ W,
             const float* __restrict__ bias, float* __restrict__ C)
{
    __shared__ __bf16 As[128][64];
    __shared__ __bf16 Bs[128][64];
    const int bid = blockIdx.x;                       // 512 blocks
    const int swz = (bid & 7) * 64 + (bid >> 3);
    const int bx  = swz & 15;
    const int by  = swz >> 4;
    gemm_tile_body<false>(A, W, bias, C, by * 128, bx * 128, 2048, 2048, As, Bs);
}

// ---------------- RoPE (in-place on bf16 q/k, layout (B,L,H*HD)) ----------------
__global__ void rope_k(__bf16* __restrict__ q, __bf16* __restrict__ k, const float* __restrict__ fc)
{
    __bf16* t = blockIdx.y ? k : q;
    const size_t e0 = ((size_t)blockIdx.x * blockDim.x + threadIdx.x) * 8;  // 4 pairs
    const int row = (int)(e0 >> 11);          // b*L + l
    const int l   = row & (LL - 1);
    const int j0  = (int)((e0 & (HDIM - 1)) >> 1);  // pair index within head
    bf16x8 v = *(bf16x8*)(t + e0);
    float4 c01 = *(const float4*)(fc + ((size_t)l * 64 + j0) * 2);
    float4 c23 = *(const float4*)(fc + ((size_t)l * 64 + j0 + 2) * 2);
    float cr[4] = { c01.x, c01.z, c23.x, c23.z };
    float ci[4] = { c01.y, c01.w, c23.y, c23.w };
    #pragma unroll
    for (int p = 0; p < 4; ++p) {
        float a = (float)v[2 * p], b = (float)v[2 * p + 1];
        v[2 * p]     = (__bf16)(a * cr[p] - b * ci[p]);
        v[2 * p + 1] = (__bf16)(a * ci[p] + b * cr[p]);
    }
    *(bf16x8*)(t + e0) = v;
}

// ---------------- latent projections via MFMA: 65536x32x128 GEMM x3 ----------
__global__ __launch_bounds__(256)
void latproj_mfma(const __bf16* __restrict__ qb, const __bf16* __restrict__ kb,
                  const __bf16* __restrict__ vb,
                  const __bf16* __restrict__ Wqcb, const __bf16* __restrict__ Wkcb,
                  const __bf16* __restrict__ Wvcb,
                  const float* __restrict__ bq, const float* __restrict__ bk,
                  const float* __restrict__ bv,
                  __bf16* __restrict__ qc, __bf16* __restrict__ kc, __bf16* __restrict__ vt)
{
    const int which = blockIdx.y;
    const __bf16* in = which == 0 ? qb : which == 1 ? kb : vb;
    const __bf16* Wb = which == 0 ? Wqcb : which == 1 ? Wkcb : Wvcb;
    const float*  bs = which == 0 ? bq : which == 1 ? bk : bv;

    const int wave = threadIdx.x >> 6;
    const int lane = threadIdx.x & 63;
    const int o    = lane & 31;
    const int hi   = lane >> 5;
    const int g0   = (blockIdx.x * 4 + wave) * 32;   // row block (g = bh*2048 + l)

    bf16x8 wf[8];
    #pragma unroll
    for (int ks = 0; ks < 8; ++ks)
        wf[ks] = *(const bf16x8*)(Wb + o * 128 + ks * 16 + hi * 8);

    const int g = g0 + o;
    const int b = g >> 15, h = (g >> 11) & 15, l = g & (LL - 1);
    const __bf16* arow = in + ((size_t)(b * LL + l)) * DD + h * HDIM;

    f32x16 C = {};
    #pragma unroll
    for (int ks = 0; ks < 8; ++ks) {
        bf16x8 af = *(const bf16x8*)(arow + ks * 16 + hi * 8);
        C = __builtin_amdgcn_mfma_f32_32x32x16_bf16(af, wf[ks], C, 0, 0, 0);
    }

    const float bias = bs[o];
    const float QSCALE = 0.17677669529663689f * 1.44269504088896340f;
    if (which == 2) {
        const int bh = g0 >> 11, l0 = g0 & (LL - 1);
        __bf16* vrow = vt + ((size_t)bh * 32 + o) * LL + l0;
        #pragma unroll
        for (int gq = 0; gq < 4; ++gq) {
            bf16x4 pk = { (__bf16)(C[gq * 4 + 0] + bias), (__bf16)(C[gq * 4 + 1] + bias),
                          (__bf16)(C[gq * 4 + 2] + bias), (__bf16)(C[gq * 4 + 3] + bias) };
            *(bf16x4*)(vrow + gq * 8 + hi * 4) = pk;
        }
    } else {
        __bf16* outp = (which == 0 ? qc : kc);
        #pragma unroll
        for (int r = 0; r < 16; ++r) {
            const int ro = (r & 3) + 8 * (r >> 2) + 4 * hi;
            float v = C[r] + bias;
            if (which == 0) v *= QSCALE;
            outp[(size_t)(g0 + ro) * 32 + o] = (__bf16)v;
        }
    }
}

// ---------------- helpers for MFMA attention ----------------
__device__ __forceinline__ unsigned pkbf2(float a, float b)
{
    union { __bf16 h[2]; unsigned u; } x;
    x.h[0] = (__bf16)a; x.h[1] = (__bf16)b;
    return x.u;
}

#if __has_builtin(__builtin_amdgcn_permlane32_swap)
typedef unsigned int uint2v __attribute__((ext_vector_type(2)));
__device__ __forceinline__ void plswap(unsigned a, unsigned b, unsigned& w_lo, unsigned& w_hi, int)
{
    uint2v r = __builtin_amdgcn_permlane32_swap(a, b, false, false);
    w_lo = r[0]; w_hi = r[1];
}
#else
__device__ __forceinline__ void plswap(unsigned a, unsigned b, unsigned& w_lo, unsigned& w_hi, int hi)
{
    unsigned ax = (unsigned)__shfl_xor((int)a, 32);
    unsigned bx = (unsigned)__shfl_xor((int)b, 32);
    w_lo = hi ? bx : a;
    w_hi = hi ? b  : ax;
}
#endif

// ---------------- split-K causal flash attention via MFMA ----------------
__global__ __launch_bounds__(64)
void attn_part(const __bf16* __restrict__ qc, const __bf16* __restrict__ kc,
               const __bf16* __restrict__ vt,
               float* __restrict__ pm, float* __restrict__ pl, float* __restrict__ po)
{
    const int id  = blockIdx.x;
    const int bhl = id & 7;
    const int c   = id >> 3;
    const int bhh = c / 160;
    const int lin = c - bhh * 160;
    int s, ci;
    if (lin < 16)      { s = lin; ci = 0; }
    else if (lin < 48) { int q = lin - 16; s = 16 + (q >> 1); ci = q & 1; }
    else if (lin < 96) { int q = lin - 48; int d = q / 3; s = 32 + d; ci = q - d * 3; }
    else               { int q = lin - 96; s = 48 + (q >> 2); ci = q & 3; }
    const int bh = bhh * 8 + bhl;

    const int lane = threadIdx.x;
    const int qcol = lane & 31;
    const int hi   = lane >> 5;

    const __bf16* qbase = qc + ((size_t)bh * LL + (size_t)s * 32) * 32;
    const __bf16* kbase = kc + (size_t)bh * LL * 32;
    const __bf16* vbase = vt + (size_t)bh * 32 * LL;

    const bf16x8 qf0 = *(const bf16x8*)(qbase + qcol * 32 + hi * 8);
    const bf16x8 qf1 = *(const bf16x8*)(qbase + qcol * 32 + 16 + hi * 8);

    float m = -1e30f, lsum = 0.f;
    f32x16 O = {};

    const int t0 = ci * 16;
    const int t1 = min(s, t0 + 15);

    const __bf16* krow = kbase + (size_t)(t0 * 32 + qcol) * 32 + hi * 8;
    const __bf16* vrow = vbase + (size_t)qcol * LL + t0 * 32 + hi * 8;
    bf16x8 kc0 = *(const bf16x8*)(krow);
    bf16x8 kc1 = *(const bf16x8*)(krow + 16);
    bf16x8 vc0 = *(const bf16x8*)(vrow);
    bf16x8 vc1 = *(const bf16x8*)(vrow + 16);

    for (int t = t0; t <= t1; ++t) {
        const int tn = (t < t1) ? t + 1 : t;
        const __bf16* krn = kbase + (size_t)(tn * 32 + qcol) * 32 + hi * 8;
        const __bf16* vrn = vbase + (size_t)qcol * LL + tn * 32 + hi * 8;
        bf16x8 kn0 = *(const bf16x8*)(krn);
        bf16x8 kn1 = *(const bf16x8*)(krn + 16);
        bf16x8 vn0 = *(const bf16x8*)(vrn);
        bf16x8 vn1 = *(const bf16x8*)(vrn + 16);

        f32x16 S = {};
        S = __builtin_amdgcn_mfma_f32_32x32x16_bf16(kc0, qf0, S, 0, 0, 0);
        S = __builtin_amdgcn_mfma_f32_32x32x16_bf16(kc1, qf1, S, 0, 0, 0);

        if (t == s) {
            #pragma unroll
            for (int r = 0; r < 16; ++r) {
                const int kl = (r & 3) + 8 * (r >> 2) + 4 * hi;
                if (kl > qcol) S[r] = -1e30f;
            }
        }
        float tm = S[0];
        #pragma unroll
        for (int r = 1; r < 16; ++r) tm = fmaxf(tm, S[r]);
        tm = fmaxf(tm, __shfl_xor(tm, 32));
        const float mn = fmaxf(m, tm);
        const float fr = exp2f(m - mn);
        m = mn;
        float p[16]; float ls = 0.f;
        #pragma unroll
        for (int r = 0; r < 16; ++r) { p[r] = exp2f(S[r] - m); ls += p[r]; }
        lsum = lsum * fr + ls;
        #pragma unroll
        for (int r = 0; r < 16; ++r) O[r] *= fr;

        unsigned w[8];
        #pragma unroll
        for (int i = 0; i < 8; ++i) w[i] = pkbf2(p[2 * i], p[2 * i + 1]);
        union PF { unsigned u[4]; bf16x8 v; } pf1, pf2;
        plswap(w[0], w[2], pf1.u[0], pf1.u[2], hi);
        plswap(w[1], w[3], pf1.u[1], pf1.u[3], hi);
        plswap(w[4], w[6], pf2.u[0], pf2.u[2], hi);
        plswap(w[5], w[7], pf2.u[1], pf2.u[3], hi);

        O = __builtin_amdgcn_mfma_f32_32x32x16_bf16(vc0, pf1.v, O, 0, 0, 0);
        O = __builtin_amdgcn_mfma_f32_32x32x16_bf16(vc1, pf2.v, O, 0, 0, 0);

        kc0 = kn0; kc1 = kn1; vc0 = vn0; vc1 = vn1;
    }

    const float L = lsum + __shfl_xor(lsum, 32);
    const size_t g = (size_t)bh * LL + (size_t)s * 32 + qcol;
    const size_t slot = g * 4 + ci;
    if (hi == 0) { pm[slot] = m; pl[slot] = L; }
    float* pp = po + slot * 32;
    #pragma unroll
    for (int g4 = 0; g4 < 4; ++g4) {
        float4 v = { O[g4 * 4 + 0], O[g4 * 4 + 1], O[g4 * 4 + 2], O[g4 * 4 + 3] };
        *(float4*)(pp + g4 * 8 + 4 * hi) = v;
    }
}

// ---------------- split-K attention combine -> bf16 ao ----------------
__global__ __launch_bounds__(256)
void attn_comb(const float* __restrict__ pm, const float* __restrict__ pl,
               const float* __restrict__ po, __bf16* __restrict__ ao)
{
    const int g = blockIdx.x * 256 + threadIdx.x;   // 0..65535
    const int i = g & (LL - 1);
    const int nch = (i >> 9) + 1;
    float m = -1e30f;
    for (int c = 0; c < nch; ++c) m = fmaxf(m, pm[(size_t)g * 4 + c]);
    float L = 0.f;
    float o[32] = {};
    for (int c = 0; c < nch; ++c) {
        const float w = exp2f(pm[(size_t)g * 4 + c] - m);
        L += w * pl[(size_t)g * 4 + c];
        const float* pp = po + ((size_t)g * 4 + c) * 32;
        #pragma unroll
        for (int d4 = 0; d4 < 8; ++d4) {
            float4 v = *(const float4*)(pp + d4 * 4);
            o[d4*4+0] += w * v.x; o[d4*4+1] += w * v.y;
            o[d4*4+2] += w * v.z; o[d4*4+3] += w * v.w;
        }
    }
    const float inv = 1.f / L;
    #pragma unroll
    for (int d8 = 0; d8 < 4; ++d8) {
        bf16x8 v;
        #pragma unroll
        for (int j = 0; j < 8; ++j) v[j] = (__bf16)(o[d8 * 8 + j] * inv);
        *(bf16x8*)(ao + (size_t)g * 32 + d8 * 8) = v;
    }
}

// ---------------- decode 32 -> 128 via MFMA: 65536x128x32 GEMM ----------------
__global__ __launch_bounds__(256)
void wd_mfma(const __bf16* __restrict__ ao, const __bf16* __restrict__ Wdb,
             const float* __restrict__ bd, __bf16* __restrict__ out)
{
    const int wave = threadIdx.x >> 6;
    const int lane = threadIdx.x & 63;
    const int o    = lane & 31;
    const int hi   = lane >> 5;
    const int g0   = (blockIdx.x * 4 + wave) * 32;

    bf16x8 wf[4][2];
    #pragma unroll
    for (int cb = 0; cb < 4; ++cb) {
        const __bf16* wrow = Wdb + (size_t)(cb * 32 + o) * 32 + hi * 8;
        wf[cb][0] = *(const bf16x8*)(wrow);
        wf[cb][1] = *(const bf16x8*)(wrow + 16);
    }

    const __bf16* arow = ao + (size_t)(g0 + o) * 32 + hi * 8;
    const bf16x8 a0 = *(const bf16x8*)(arow);
    const bf16x8 a1 = *(const bf16x8*)(arow + 16);

    f32x16 C[4] = {};
    #pragma unroll
    for (int cb = 0; cb < 4; ++cb) {
        C[cb] = __builtin_amdgcn_mfma_f32_32x32x16_bf16(a0, wf[cb][0], C[cb], 0, 0, 0);
        C[cb] = __builtin_amdgcn_mfma_f32_32x32x16_bf16(a1, wf[cb][1], C[cb], 0, 0, 0);
    }

    const int b = g0 >> 15, h = (g0 >> 11) & 15, l0 = g0 & (LL - 1);
    #pragma unroll
    for (int cb = 0; cb < 4; ++cb) {
        const float bias = bd[cb * 32 + o];
        #pragma unroll
        for (int r = 0; r < 16; ++r) {
            const int ro = (r & 3) + 8 * (r >> 2) + 4 * hi;
            out[(size_t)(b * LL + l0 + ro) * DD + h * HDIM + cb * 32 + o] =
                (__bf16)(C[cb][r] + bias);
        }
    }
}

extern "C" void kernel_launch(void* const* d_in, const int* in_sizes, int n_in,
                              void* d_out, int out_size, void* d_ws, size_t ws_size,
                              hipStream_t stream)
{
    const float* x   = (const float*)d_in[0];
    const float* fc  = (const float*)d_in[1];
    const float* Wq  = (const float*)d_in[2];
    const float* bq  = (const float*)d_in[3];
    const float* Wk  = (const float*)d_in[4];
    const float* bk  = (const float*)d_in[5];
    const float* Wv  = (const float*)d_in[6];
    const float* bv  = (const float*)d_in[7];
    const float* Wqc = (const float*)d_in[8];
    const float* bqc = (const float*)d_in[9];
    const float* Wkc = (const float*)d_in[10];
    const float* bkc = (const float*)d_in[11];
    const float* Wvc = (const float*)d_in[12];
    const float* bvc = (const float*)d_in[13];
    const float* Wd  = (const float*)d_in[14];
    const float* bd  = (const float*)d_in[15];
    const float* Wo  = (const float*)d_in[16];
    const float* bo  = (const float*)d_in[17];
    float* out = (float*)d_out;

    // workspace layout (144 MiB total)
    char* w = (char*)d_ws;
    __bf16* xb  = (__bf16*)w; w += (size_t)4096 * 2048 * 2;   // dead after QKV GEMM
    __bf16* Wqb = (__bf16*)w; w += (size_t)2048 * 2048 * 2;
    __bf16* Wkb = (__bf16*)w; w += (size_t)2048 * 2048 * 2;
    __bf16* Wvb = (__bf16*)w; w += (size_t)2048 * 2048 * 2;
    __bf16* Wob = (__bf16*)w; w += (size_t)2048 * 2048 * 2;   // live till end
    __bf16* qb  = (__bf16*)w; w += (size_t)4096 * 2048 * 2;
    __bf16* kb  = (__bf16*)w; w += (size_t)4096 * 2048 * 2;
    __bf16* vb  = (__bf16*)w; w += (size_t)4096 * 2048 * 2;
    __bf16* qcbf = (__bf16*)w; w += (size_t)65536 * 32 * 4;  // bf16 in f32-sized slot (half free)
    __bf16* kcbf = (__bf16*)w; w += (size_t)65536 * 32 * 4;
    __bf16* vtbf = (__bf16*)w; w += (size_t)65536 * 32 * 4;
    __bf16* aobf = (__bf16*)w; w += (size_t)65536 * 32 * 4;  // bf16 ao (half slot free)
    __bf16* adb = (__bf16*)w;  w += (size_t)4096 * 2048 * 2;

    // small bf16 weights in the unused upper half of the qcbf slot (4 MiB free)
    __bf16* Wqcb = (__bf16*)((char*)qcbf + 4194304);
    __bf16* Wkcb = Wqcb + 4096;
    __bf16* Wvcb = Wkcb + 4096;
    __bf16* Wdb  = Wvcb + 4096;

    // attention partials alias xb..Wvb (dead by then): 33.5M + 1M + 1M < 40M
    float* po = (float*)d_ws;
    float* pm = (float*)((char*)d_ws + 33554432);
    float* pl = (float*)((char*)d_ws + 34603008);

    if (ws_size < (size_t)150994944) return;  // fail loudly (zero output) rather than corrupt

    cvt_f32_bf16<<<8192, 256, 0, stream>>>(x, xb, 2097152);
    cvt_w_big<<<dim3(4096, 4), 256, 0, stream>>>(Wq, Wk, Wv, Wo, Wqb, Wkb, Wvb, Wob);
    cvt_w4<<<dim3(4, 4), 256, 0, stream>>>(Wqc, Wkc, Wvc, Wd, Wqcb, Wkcb, Wvcb, Wdb);

    gemm_qkv<<<1536, 256, 0, stream>>>(xb, Wqb, Wkb, Wvb, bq, bk, bv, qb, kb, vb);

    rope_k<<<dim3(4096, 2), 256, 0, stream>>>(qb, kb, fc);

    latproj_mfma<<<dim3(512, 3), 256, 0, stream>>>(qb, kb, vb, Wqcb, Wkcb, Wvcb,
                                                   bqc, bkc, bvc, qcbf, kcbf, vtbf);

    attn_part<<<5120, 64, 0, stream>>>(qcbf, kcbf, vtbf, pm, pl, po);
    attn_comb<<<256, 256, 0, stream>>>(pm, pl, po, aobf);

    wd_mfma<<<512, 256, 0, stream>>>(aobf, Wdb, bd, adb);

    gemm_wo<<<512, 256, 0, stream>>>(adb, Wob, bo, out);
}